// Round 8
// baseline (213.650 us; speedup 1.0000x reference)
//
#include <hip/hip_runtime.h>
#include <math.h>

// GaussianMixture log-density via f16 MFMA, fused single kernel, round 8.
//
//   e[k,n] = sum_j C[k][j] * F[j][n]   (base-2 exponent, fp32 MFMA accum)
//     coeff row  (A operand):  [ a2[0..19] , b2[0..19] , L2 , 0.. ]
//     feature col(B operand):  [ x^2_0..19 , x_0..19 , 1 , 0.. ]
//   out[n] = ln( sum_k exp2(e[k,n]) ) + LOG_NORM
//
// R7 lesson: not LDS-bound -- per-chunk critical path (unprefetched global
// load -> pack -> MFMA -> 44-deep exp2 add chain -> 2 serial shuffles) at
// 3 waves/SIMD. R8: single-buffer register prefetch of the next chunk's
// samples (latency hides under current chunk's MFMA+exp2), 4 independent
// exp2 partials, and all cross-lane reductions/stores deferred to the end.

#define DIMS     20
#define MULT     8
#define K_COMP   168
#define KC_PAD   176            // 11 tiles of 16 components
#define BROW     72             // halfs per coeff row: 144 B stride
#define BASE_COV 0.1f
#define LOG2E    1.4426950408889634f
#define LN2      0.6931471805599453f
#define LOG_NORM -18.378770664093453f
#define CPW      8              // 16-sample chunks per wave
#define NB       1024           // NB * 4 waves * CPW * 16 = 524288 exactly

typedef _Float16 f16x8 __attribute__((ext_vector_type(8)));
typedef _Float16 f16x2 __attribute__((ext_vector_type(2)));
typedef float    f32x4 __attribute__((ext_vector_type(4)));
typedef unsigned int uint;
typedef uint u32x4 __attribute__((ext_vector_type(4)));

__device__ __forceinline__ uint pk(float lo, float hi) {
    return __builtin_bit_cast(uint, __builtin_amdgcn_cvt_pkrtz(lo, hi));
}
__device__ __forceinline__ uint pksq(uint a) {     // v_pk_mul_f16: (lo^2, hi^2)
    f16x2 v = __builtin_bit_cast(f16x2, a);
    return __builtin_bit_cast(uint, (f16x2)(v * v));
}

__global__ __launch_bounds__(256, 3) void gm_fused(const float* __restrict__ sample,
                                                   const float* __restrict__ alpha,
                                                   const float* __restrict__ mu,
                                                   const float* __restrict__ cov,
                                                   float* __restrict__ out) {
    __shared__ __attribute__((aligned(16))) _Float16 lds_T[KC_PAD][BROW];
    __shared__ float sh_logZ;
    const int tid = threadIdx.x;

    // ---- phase 1: zero the coefficient table ----
    uint* bz = (uint*)&lds_T[0][0];
    for (int i = tid; i < KC_PAD * BROW / 2; i += 256) bz[i] = 0u;
    __syncthreads();

    // ---- phase 2: softmax normalizer (wave 0) ----
    if (tid < 64) {
        float a0 = (tid       < K_COMP) ? alpha[tid]       : -1e30f;
        float a1 = (tid + 64  < K_COMP) ? alpha[tid + 64]  : -1e30f;
        float a2 = (tid + 128 < K_COMP) ? alpha[tid + 128] : -1e30f;
        float m = fmaxf(fmaxf(a0, a1), a2);
        for (int msk = 32; msk; msk >>= 1) m = fmaxf(m, __shfl_xor(m, msk, 64));
        float s = __expf(a0 - m) + __expf(a1 - m) + __expf(a2 - m);
        for (int msk = 32; msk; msk >>= 1) s += __shfl_xor(s, msk, 64);
        if (tid == 0) sh_logZ = m + __logf(s);
    }
    __syncthreads();

    // ---- phase 3: fill coefficient rows (one thread per component) ----
    if (tid < K_COMP) {
        const int   n  = tid;
        const int   i  = n / MULT;
        const float fi = (float)i;
        const float var = 1.0f;                       // EPS^2, EPS = 1.0
        float logdet = fi * __logf(var) + ((float)DIMS - fi) * __logf(BASE_COV);
        const float4* cvp = (const float4*)(cov + n * DIMS);
        const float4* mup = (const float4*)(mu + n * DIMS);
        float4 c0 = cvp[0], c1 = cvp[1], c2 = cvp[2], c3 = cvp[3], c4 = cvp[4];
        float4 m0 = mup[0], m1 = mup[1], m2 = mup[2], m3 = mup[3], m4 = mup[4];
        float C = 0.0f;
        auto emit = [&](int d, float cc, float mm) {
            float scale = (d < i) ? var : 1.0f;
            float inv   = 1.0f / (cc * scale);
            C += mm * mm * inv;
            lds_T[n][d]        = (_Float16)(-0.5f * inv * LOG2E);
            lds_T[n][DIMS + d] = (_Float16)(mm * inv * LOG2E);
        };
        emit( 0, c0.x, m0.x); emit( 1, c0.y, m0.y); emit( 2, c0.z, m0.z); emit( 3, c0.w, m0.w);
        emit( 4, c1.x, m1.x); emit( 5, c1.y, m1.y); emit( 6, c1.z, m1.z); emit( 7, c1.w, m1.w);
        emit( 8, c2.x, m2.x); emit( 9, c2.y, m2.y); emit(10, c2.z, m2.z); emit(11, c2.w, m2.w);
        emit(12, c3.x, m3.x); emit(13, c3.y, m3.y); emit(14, c3.z, m3.z); emit(15, c3.w, m3.w);
        emit(16, c4.x, m4.x); emit(17, c4.y, m4.y); emit(18, c4.z, m4.z); emit(19, c4.w, m4.w);
        float L2 = ((alpha[n] - sh_logZ) - 0.5f * logdet - 0.5f * C) * LOG2E;
        lds_T[n][2 * DIMS] = (_Float16)L2;
    } else if (tid < KC_PAD) {
        lds_T[tid][2 * DIMS] = (_Float16)(-65504.0f); // pad comps -> exp2 -> 0
    }
    __syncthreads();

    // ---- phase 4: hoist coefficient fragments into registers (88 VGPRs) ----
    const int w = tid >> 6, l = tid & 63, q = l >> 4, c = l & 15;
    const bool qa = (q & 1) != 0, qb = (q & 2) != 0;
    const uint onezero = 0x00003C00u;                 // pk(1.0h, 0.0h)
    const f32x4 zero = { 0.f, 0.f, 0.f, 0.f };

#define LOAD_CF(T)                                                              \
    const f16x8 cf1_##T = *(const f16x8*)&lds_T[(T) * 16 + c][q * 8];           \
    const f16x8 cf2_##T = *(const f16x8*)&lds_T[(T) * 16 + c][32 + q * 8];
    LOAD_CF(0) LOAD_CF(1) LOAD_CF(2) LOAD_CF(3) LOAD_CF(4) LOAD_CF(5)
    LOAD_CF(6) LOAD_CF(7) LOAD_CF(8) LOAD_CF(9) LOAD_CF(10)
#undef LOAD_CF

    // ---- phase 5: serial chunks, next-chunk register prefetch ----
    const int base = blockIdx.x * (64 * CPW) + w * 16;

    // prefetch chunk 0
    const float4* rp0 = (const float4*)(sample + (size_t)(base + c) * DIMS);
    float4 r0 = rp0[0], r1 = rp0[1], r2 = rp0[2], r3 = rp0[3], r4 = rp0[4];

#define DO_TILE(T)                                                              \
        {                                                                       \
            f32x4 acc = __builtin_amdgcn_mfma_f32_16x16x32_f16(cf1_##T, sf1, zero, 0, 0, 0); \
            acc       = __builtin_amdgcn_mfma_f32_16x16x32_f16(cf2_##T, sf2, acc,  0, 0, 0); \
            p0 += __builtin_amdgcn_exp2f(acc[0]);                               \
            p1 += __builtin_amdgcn_exp2f(acc[1]);                               \
            p2 += __builtin_amdgcn_exp2f(acc[2]);                               \
            p3 += __builtin_amdgcn_exp2f(acc[3]);                               \
        }

#define DO_CHUNK(CC)                                                            \
    float dens_##CC;                                                            \
    {                                                                           \
        /* pack current chunk (consumes r0..r4) */                              \
        uint q0 = pk(r0.x, r0.y), q1 = pk(r0.z, r0.w);                          \
        uint q2 = pk(r1.x, r1.y), q3 = pk(r1.z, r1.w);                          \
        uint q4 = pk(r2.x, r2.y), q5 = pk(r2.z, r2.w);                          \
        uint q6 = pk(r3.x, r3.y), q7 = pk(r3.z, r3.w);                          \
        uint q8 = pk(r4.x, r4.y), q9 = pk(r4.z, r4.w);                          \
        /* r0..r4 now dead: issue next chunk's loads (latency hides below) */   \
        if ((CC) + 1 < CPW) {                                                   \
            const float4* np = (const float4*)(sample + (size_t)(base + ((CC) + 1) * 64 + c) * DIMS); \
            r0 = np[0]; r1 = np[1]; r2 = np[2]; r3 = np[3]; r4 = np[4];         \
        }                                                                       \
        uint s0 = pksq(q0), s1 = pksq(q1), s2 = pksq(q2), s3 = pksq(q3);        \
        uint s4 = pksq(q4), s5 = pksq(q5), s6 = pksq(q6), s7 = pksq(q7);        \
        uint s8 = pksq(q8), s9 = pksq(q9);                                      \
        uint f1_0 = qb ? (qa ? q2 : s8) : (qa ? s4 : s0);                       \
        uint f1_1 = qb ? (qa ? q3 : s9) : (qa ? s5 : s1);                       \
        uint f1_2 = qb ? (qa ? q4 : q0) : (qa ? s6 : s2);                       \
        uint f1_3 = qb ? (qa ? q5 : q1) : (qa ? s7 : s3);                       \
        uint f2_0 = qb ? 0u : (qa ? onezero : q6);                              \
        uint f2_1 = qb ? 0u : (qa ? 0u : q7);                                   \
        uint f2_2 = qb ? 0u : (qa ? 0u : q8);                                   \
        uint f2_3 = qb ? 0u : (qa ? 0u : q9);                                   \
        u32x4 w1 = { f1_0, f1_1, f1_2, f1_3 };                                  \
        u32x4 w2 = { f2_0, f2_1, f2_2, f2_3 };                                  \
        f16x8 sf1 = __builtin_bit_cast(f16x8, w1);                              \
        f16x8 sf2 = __builtin_bit_cast(f16x8, w2);                              \
        float p0 = 0.f, p1 = 0.f, p2 = 0.f, p3 = 0.f;  /* 4 independent chains */ \
        DO_TILE(0) DO_TILE(1) DO_TILE(2) DO_TILE(3) DO_TILE(4) DO_TILE(5)       \
        DO_TILE(6) DO_TILE(7) DO_TILE(8) DO_TILE(9) DO_TILE(10)                 \
        dens_##CC = (p0 + p1) + (p2 + p3);                                      \
    }

    DO_CHUNK(0) DO_CHUNK(1) DO_CHUNK(2) DO_CHUNK(3)
    DO_CHUNK(4) DO_CHUNK(5) DO_CHUNK(6) DO_CHUNK(7)
#undef DO_CHUNK
#undef DO_TILE

    // ---- phase 6: deferred cross-lane reductions + stores (pipelined) ----
#define FINISH(CC)                                                              \
    {                                                                           \
        float dn = dens_##CC;                                                   \
        dn += __shfl_xor(dn, 16, 64);                                           \
        dn += __shfl_xor(dn, 32, 64);                                           \
        if (l < 16) out[base + (CC) * 64 + l] = LN2 * __builtin_amdgcn_logf(dn) + LOG_NORM; \
    }
    FINISH(0) FINISH(1) FINISH(2) FINISH(3)
    FINISH(4) FINISH(5) FINISH(6) FINISH(7)
#undef FINISH
}

extern "C" void kernel_launch(void* const* d_in, const int* in_sizes, int n_in,
                              void* d_out, int out_size, void* d_ws, size_t ws_size,
                              hipStream_t stream) {
    const float* sample = (const float*)d_in[0];
    const float* alpha  = (const float*)d_in[1];
    const float* mu     = (const float*)d_in[2];
    const float* cov    = (const float*)d_in[3];
    float* out = (float*)d_out;
    // N = 524288 = NB * 4 waves * CPW * 16 -- grid covers the range exactly.
    gm_fused<<<NB, 256, 0, stream>>>(sample, alpha, mu, cov, out);
}

// Round 9
// 97.871 us; speedup vs baseline: 2.1830x; 2.1830x over previous
//
#include <hip/hip_runtime.h>
#include <math.h>

// GaussianMixture log-density via f16 MFMA, fused single kernel, round 9.
//
//   e[k,n] = sum_j C[k][j] * F[j][n]   (base-2 exponent, fp32 MFMA accum)
//     coeff row  (A operand):  [ a2[0..19] , b2[0..19] , L2 , 0.. ]
//     feature col(B operand):  [ x^2_0..19 , x_0..19 , 1 , 0.. ]
//   out[n] = ln( sum_k exp2(e[k,n]) ) + LOG_NORM
//
// R8 lesson: free-floating "depth-1" prefetch lets the scheduler hoist loads
// for many chunks ahead -> pressure blows past the 170-VGPR budget -> spiller
// evicts the hoisted coeff fragments (VGPR=84, 330 MB scratch traffic).
// R9 = R7 + prefetch whose ADDRESS is tied to the current chunk's packed
// fragment via empty asm (enforced depth-1), + 4 independent exp2 partials.

#define DIMS     20
#define MULT     8
#define K_COMP   168
#define KC_PAD   176            // 11 tiles of 16 components
#define BROW     72             // halfs per coeff row: 144 B stride
#define BASE_COV 0.1f
#define LOG2E    1.4426950408889634f
#define LN2      0.6931471805599453f
#define LOG_NORM -18.378770664093453f
#define CPW      8              // 16-sample chunks per wave
#define NB       1024           // NB * 4 waves * CPW * 16 = 524288 exactly

typedef _Float16 f16x8 __attribute__((ext_vector_type(8)));
typedef _Float16 f16x2 __attribute__((ext_vector_type(2)));
typedef float    f32x4 __attribute__((ext_vector_type(4)));
typedef unsigned int uint;
typedef uint u32x4 __attribute__((ext_vector_type(4)));

__device__ __forceinline__ uint pk(float lo, float hi) {
    return __builtin_bit_cast(uint, __builtin_amdgcn_cvt_pkrtz(lo, hi));
}
__device__ __forceinline__ uint pksq(uint a) {     // v_pk_mul_f16: (lo^2, hi^2)
    f16x2 v = __builtin_bit_cast(f16x2, a);
    return __builtin_bit_cast(uint, (f16x2)(v * v));
}

__global__ __launch_bounds__(256, 3) void gm_fused(const float* __restrict__ sample,
                                                   const float* __restrict__ alpha,
                                                   const float* __restrict__ mu,
                                                   const float* __restrict__ cov,
                                                   float* __restrict__ out) {
    __shared__ __attribute__((aligned(16))) _Float16 lds_T[KC_PAD][BROW];
    __shared__ float sh_logZ;
    const int tid = threadIdx.x;

    // ---- phase 1: zero the coefficient table ----
    uint* bz = (uint*)&lds_T[0][0];
    for (int i = tid; i < KC_PAD * BROW / 2; i += 256) bz[i] = 0u;
    __syncthreads();

    // ---- phase 2: softmax normalizer (wave 0) ----
    if (tid < 64) {
        float a0 = (tid       < K_COMP) ? alpha[tid]       : -1e30f;
        float a1 = (tid + 64  < K_COMP) ? alpha[tid + 64]  : -1e30f;
        float a2 = (tid + 128 < K_COMP) ? alpha[tid + 128] : -1e30f;
        float m = fmaxf(fmaxf(a0, a1), a2);
        for (int msk = 32; msk; msk >>= 1) m = fmaxf(m, __shfl_xor(m, msk, 64));
        float s = __expf(a0 - m) + __expf(a1 - m) + __expf(a2 - m);
        for (int msk = 32; msk; msk >>= 1) s += __shfl_xor(s, msk, 64);
        if (tid == 0) sh_logZ = m + __logf(s);
    }
    __syncthreads();

    // ---- phase 3: fill coefficient rows (one thread per component) ----
    if (tid < K_COMP) {
        const int   n  = tid;
        const int   i  = n / MULT;
        const float fi = (float)i;
        const float var = 1.0f;                       // EPS^2, EPS = 1.0
        float logdet = fi * __logf(var) + ((float)DIMS - fi) * __logf(BASE_COV);
        const float4* cvp = (const float4*)(cov + n * DIMS);
        const float4* mup = (const float4*)(mu + n * DIMS);
        float4 c0 = cvp[0], c1 = cvp[1], c2 = cvp[2], c3 = cvp[3], c4 = cvp[4];
        float4 m0 = mup[0], m1 = mup[1], m2 = mup[2], m3 = mup[3], m4 = mup[4];
        float C = 0.0f;
        auto emit = [&](int d, float cc, float mm) {
            float scale = (d < i) ? var : 1.0f;
            float inv   = 1.0f / (cc * scale);
            C += mm * mm * inv;
            lds_T[n][d]        = (_Float16)(-0.5f * inv * LOG2E);
            lds_T[n][DIMS + d] = (_Float16)(mm * inv * LOG2E);
        };
        emit( 0, c0.x, m0.x); emit( 1, c0.y, m0.y); emit( 2, c0.z, m0.z); emit( 3, c0.w, m0.w);
        emit( 4, c1.x, m1.x); emit( 5, c1.y, m1.y); emit( 6, c1.z, m1.z); emit( 7, c1.w, m1.w);
        emit( 8, c2.x, m2.x); emit( 9, c2.y, m2.y); emit(10, c2.z, m2.z); emit(11, c2.w, m2.w);
        emit(12, c3.x, m3.x); emit(13, c3.y, m3.y); emit(14, c3.z, m3.z); emit(15, c3.w, m3.w);
        emit(16, c4.x, m4.x); emit(17, c4.y, m4.y); emit(18, c4.z, m4.z); emit(19, c4.w, m4.w);
        float L2 = ((alpha[n] - sh_logZ) - 0.5f * logdet - 0.5f * C) * LOG2E;
        lds_T[n][2 * DIMS] = (_Float16)L2;
    } else if (tid < KC_PAD) {
        lds_T[tid][2 * DIMS] = (_Float16)(-65504.0f); // pad comps -> exp2 -> 0
    }
    __syncthreads();

    // ---- phase 4: hoist coefficient fragments into registers (88 VGPRs) ----
    const int w = tid >> 6, l = tid & 63, q = l >> 4, c = l & 15;
    const bool qa = (q & 1) != 0, qb = (q & 2) != 0;
    const uint onezero = 0x00003C00u;                 // pk(1.0h, 0.0h)
    const f32x4 zero = { 0.f, 0.f, 0.f, 0.f };

#define LOAD_CF(T)                                                              \
    const f16x8 cf1_##T = *(const f16x8*)&lds_T[(T) * 16 + c][q * 8];           \
    const f16x8 cf2_##T = *(const f16x8*)&lds_T[(T) * 16 + c][32 + q * 8];
    LOAD_CF(0) LOAD_CF(1) LOAD_CF(2) LOAD_CF(3) LOAD_CF(4) LOAD_CF(5)
    LOAD_CF(6) LOAD_CF(7) LOAD_CF(8) LOAD_CF(9) LOAD_CF(10)
#undef LOAD_CF

    // ---- phase 5: serial chunks; depth-1 prefetch enforced via asm dep ----
    const int base = blockIdx.x * (64 * CPW) + w * 16;

    // prefetch chunk 0
    const float4* rp0 = (const float4*)(sample + (size_t)(base + c) * DIMS);
    float4 r0 = rp0[0], r1 = rp0[1], r2 = rp0[2], r3 = rp0[3], r4 = rp0[4];

#define DO_TILE(T)                                                              \
        {                                                                       \
            f32x4 acc = __builtin_amdgcn_mfma_f32_16x16x32_f16(cf1_##T, sf1, zero, 0, 0, 0); \
            acc       = __builtin_amdgcn_mfma_f32_16x16x32_f16(cf2_##T, sf2, acc,  0, 0, 0); \
            p0 += __builtin_amdgcn_exp2f(acc[0]);                               \
            p1 += __builtin_amdgcn_exp2f(acc[1]);                               \
            p2 += __builtin_amdgcn_exp2f(acc[2]);                               \
            p3 += __builtin_amdgcn_exp2f(acc[3]);                               \
        }

#define DO_CHUNK(CC)                                                            \
    {                                                                           \
        /* pack current chunk (consumes r0..r4) */                              \
        uint q0 = pk(r0.x, r0.y), q1 = pk(r0.z, r0.w);                          \
        uint q2 = pk(r1.x, r1.y), q3 = pk(r1.z, r1.w);                          \
        uint q4 = pk(r2.x, r2.y), q5 = pk(r2.z, r2.w);                          \
        uint q6 = pk(r3.x, r3.y), q7 = pk(r3.z, r3.w);                          \
        uint q8 = pk(r4.x, r4.y), q9 = pk(r4.z, r4.w);                          \
        uint s0 = pksq(q0), s1 = pksq(q1), s2 = pksq(q2), s3 = pksq(q3);        \
        uint s4 = pksq(q4), s5 = pksq(q5), s6 = pksq(q6), s7 = pksq(q7);        \
        uint s8 = pksq(q8), s9 = pksq(q9);                                      \
        uint f1_0 = qb ? (qa ? q2 : s8) : (qa ? s4 : s0);                       \
        uint f1_1 = qb ? (qa ? q3 : s9) : (qa ? s5 : s1);                       \
        uint f1_2 = qb ? (qa ? q4 : q0) : (qa ? s6 : s2);                       \
        uint f1_3 = qb ? (qa ? q5 : q1) : (qa ? s7 : s3);                       \
        uint f2_0 = qb ? 0u : (qa ? onezero : q6);                              \
        uint f2_1 = qb ? 0u : (qa ? 0u : q7);                                   \
        uint f2_2 = qb ? 0u : (qa ? 0u : q8);                                   \
        uint f2_3 = qb ? 0u : (qa ? 0u : q9);                                   \
        u32x4 w1 = { f1_0, f1_1, f1_2, f1_3 };                                  \
        u32x4 w2 = { f2_0, f2_1, f2_2, f2_3 };                                  \
        f16x8 sf1 = __builtin_bit_cast(f16x8, w1);                              \
        f16x8 sf2 = __builtin_bit_cast(f16x8, w2);                              \
        /* depth-1 prefetch: address depends on f1_0 via opaque asm, so the  */ \
        /* scheduler cannot hoist these loads above this chunk's pack, and   */ \
        /* (transitively) cannot run more than one chunk ahead.              */ \
        if ((CC) + 1 < CPW) {                                                   \
            uint dep = f1_0;                                                    \
            asm volatile("" : "+v"(dep));                                       \
            dep &= 0u; /* opaque zero */                                        \
            const float4* np = (const float4*)(sample                           \
                + (size_t)(base + ((CC) + 1) * 64 + c) * DIMS + dep);           \
            r0 = np[0]; r1 = np[1]; r2 = np[2]; r3 = np[3]; r4 = np[4];         \
        }                                                                       \
        float p0 = 0.f, p1 = 0.f, p2 = 0.f, p3 = 0.f;  /* 4 indep chains */     \
        DO_TILE(0) DO_TILE(1) DO_TILE(2) DO_TILE(3) DO_TILE(4) DO_TILE(5)       \
        DO_TILE(6) DO_TILE(7) DO_TILE(8) DO_TILE(9) DO_TILE(10)                 \
        float dens = (p0 + p1) + (p2 + p3);                                     \
        dens += __shfl_xor(dens, 16, 64);                                       \
        dens += __shfl_xor(dens, 32, 64);                                       \
        if (l < 16)                                                             \
            out[base + (CC) * 64 + l] = LN2 * __builtin_amdgcn_logf(dens) + LOG_NORM; \
    }

    DO_CHUNK(0) DO_CHUNK(1) DO_CHUNK(2) DO_CHUNK(3)
    DO_CHUNK(4) DO_CHUNK(5) DO_CHUNK(6) DO_CHUNK(7)
#undef DO_CHUNK
#undef DO_TILE
}

extern "C" void kernel_launch(void* const* d_in, const int* in_sizes, int n_in,
                              void* d_out, int out_size, void* d_ws, size_t ws_size,
                              hipStream_t stream) {
    const float* sample = (const float*)d_in[0];
    const float* alpha  = (const float*)d_in[1];
    const float* mu     = (const float*)d_in[2];
    const float* cov    = (const float*)d_in[3];
    float* out = (float*)d_out;
    // N = 524288 = NB * 4 waves * CPW * 16 -- grid covers the range exactly.
    gm_fused<<<NB, 256, 0, stream>>>(sample, alpha, mu, cov, out);
}

// Round 10
// 97.568 us; speedup vs baseline: 2.1898x; 1.0031x over previous
//
#include <hip/hip_runtime.h>
#include <math.h>

// GaussianMixture log-density via f16 MFMA, fused single kernel, round 10.
//
//   e[k,n] = sum_j C[k][j] * F[j][n]   (base-2 exponent, fp32 MFMA accum)
//     coeff row  (A operand):  [ a2[0..19] , b2[0..19] , L2 , 0.. ]
//     feature col(B operand):  [ x^2_0..19 , x_0..19 , 1 , 0.. ]
//   out[n] = ln( sum_k exp2(e[k,n]) ) + LOG_NORM
//
// R9 was an invalid experiment: `dep &= 0` constant-folded, deleting the asm
// dependency -- the "depth-1 prefetch" never existed. R10 zeroes dep INSIDE
// the asm (v_and_b32 dep, 0, dep), opaque to the compiler: chunk CC+1's loads
// are truly pinned after chunk CC's pack (depth-1, no R8 pressure blowup),
// giving each global load ~1.7k cyc of cover at 3 waves/SIMD.

#define DIMS     20
#define MULT     8
#define K_COMP   168
#define KC_PAD   176            // 11 tiles of 16 components
#define BROW     72             // halfs per coeff row: 144 B stride
#define BASE_COV 0.1f
#define LOG2E    1.4426950408889634f
#define LN2      0.6931471805599453f
#define LOG_NORM -18.378770664093453f
#define CPW      8              // 16-sample chunks per wave
#define NB       1024           // NB * 4 waves * CPW * 16 = 524288 exactly

typedef _Float16 f16x8 __attribute__((ext_vector_type(8)));
typedef _Float16 f16x2 __attribute__((ext_vector_type(2)));
typedef float    f32x4 __attribute__((ext_vector_type(4)));
typedef unsigned int uint;
typedef uint u32x4 __attribute__((ext_vector_type(4)));

__device__ __forceinline__ uint pk(float lo, float hi) {
    return __builtin_bit_cast(uint, __builtin_amdgcn_cvt_pkrtz(lo, hi));
}
__device__ __forceinline__ uint pksq(uint a) {     // v_pk_mul_f16: (lo^2, hi^2)
    f16x2 v = __builtin_bit_cast(f16x2, a);
    return __builtin_bit_cast(uint, (f16x2)(v * v));
}

__global__ __launch_bounds__(256, 3) void gm_fused(const float* __restrict__ sample,
                                                   const float* __restrict__ alpha,
                                                   const float* __restrict__ mu,
                                                   const float* __restrict__ cov,
                                                   float* __restrict__ out) {
    __shared__ __attribute__((aligned(16))) _Float16 lds_T[KC_PAD][BROW];
    __shared__ float sh_logZ;
    const int tid = threadIdx.x;

    // ---- phase 1: zero the coefficient table ----
    uint* bz = (uint*)&lds_T[0][0];
    for (int i = tid; i < KC_PAD * BROW / 2; i += 256) bz[i] = 0u;
    __syncthreads();

    // ---- phase 2: softmax normalizer (wave 0) ----
    if (tid < 64) {
        float a0 = (tid       < K_COMP) ? alpha[tid]       : -1e30f;
        float a1 = (tid + 64  < K_COMP) ? alpha[tid + 64]  : -1e30f;
        float a2 = (tid + 128 < K_COMP) ? alpha[tid + 128] : -1e30f;
        float m = fmaxf(fmaxf(a0, a1), a2);
        for (int msk = 32; msk; msk >>= 1) m = fmaxf(m, __shfl_xor(m, msk, 64));
        float s = __expf(a0 - m) + __expf(a1 - m) + __expf(a2 - m);
        for (int msk = 32; msk; msk >>= 1) s += __shfl_xor(s, msk, 64);
        if (tid == 0) sh_logZ = m + __logf(s);
    }
    __syncthreads();

    // ---- phase 3: fill coefficient rows (one thread per component) ----
    if (tid < K_COMP) {
        const int   n  = tid;
        const int   i  = n / MULT;
        const float fi = (float)i;
        const float var = 1.0f;                       // EPS^2, EPS = 1.0
        float logdet = fi * __logf(var) + ((float)DIMS - fi) * __logf(BASE_COV);
        const float4* cvp = (const float4*)(cov + n * DIMS);
        const float4* mup = (const float4*)(mu + n * DIMS);
        float4 c0 = cvp[0], c1 = cvp[1], c2 = cvp[2], c3 = cvp[3], c4 = cvp[4];
        float4 m0 = mup[0], m1 = mup[1], m2 = mup[2], m3 = mup[3], m4 = mup[4];
        float C = 0.0f;
        auto emit = [&](int d, float cc, float mm) {
            float scale = (d < i) ? var : 1.0f;
            float inv   = 1.0f / (cc * scale);
            C += mm * mm * inv;
            lds_T[n][d]        = (_Float16)(-0.5f * inv * LOG2E);
            lds_T[n][DIMS + d] = (_Float16)(mm * inv * LOG2E);
        };
        emit( 0, c0.x, m0.x); emit( 1, c0.y, m0.y); emit( 2, c0.z, m0.z); emit( 3, c0.w, m0.w);
        emit( 4, c1.x, m1.x); emit( 5, c1.y, m1.y); emit( 6, c1.z, m1.z); emit( 7, c1.w, m1.w);
        emit( 8, c2.x, m2.x); emit( 9, c2.y, m2.y); emit(10, c2.z, m2.z); emit(11, c2.w, m2.w);
        emit(12, c3.x, m3.x); emit(13, c3.y, m3.y); emit(14, c3.z, m3.z); emit(15, c3.w, m3.w);
        emit(16, c4.x, m4.x); emit(17, c4.y, m4.y); emit(18, c4.z, m4.z); emit(19, c4.w, m4.w);
        float L2 = ((alpha[n] - sh_logZ) - 0.5f * logdet - 0.5f * C) * LOG2E;
        lds_T[n][2 * DIMS] = (_Float16)L2;
    } else if (tid < KC_PAD) {
        lds_T[tid][2 * DIMS] = (_Float16)(-65504.0f); // pad comps -> exp2 -> 0
    }
    __syncthreads();

    // ---- phase 4: hoist coefficient fragments into registers (88 VGPRs) ----
    const int w = tid >> 6, l = tid & 63, q = l >> 4, c = l & 15;
    const bool qa = (q & 1) != 0, qb = (q & 2) != 0;
    const uint onezero = 0x00003C00u;                 // pk(1.0h, 0.0h)
    const f32x4 zero = { 0.f, 0.f, 0.f, 0.f };

#define LOAD_CF(T)                                                              \
    const f16x8 cf1_##T = *(const f16x8*)&lds_T[(T) * 16 + c][q * 8];           \
    const f16x8 cf2_##T = *(const f16x8*)&lds_T[(T) * 16 + c][32 + q * 8];
    LOAD_CF(0) LOAD_CF(1) LOAD_CF(2) LOAD_CF(3) LOAD_CF(4) LOAD_CF(5)
    LOAD_CF(6) LOAD_CF(7) LOAD_CF(8) LOAD_CF(9) LOAD_CF(10)
#undef LOAD_CF

    // ---- phase 5: serial chunks; depth-1 prefetch enforced via opaque asm ----
    const int base = blockIdx.x * (64 * CPW) + w * 16;

    // prefetch chunk 0
    const float4* rp0 = (const float4*)(sample + (size_t)(base + c) * DIMS);
    float4 r0 = rp0[0], r1 = rp0[1], r2 = rp0[2], r3 = rp0[3], r4 = rp0[4];

#define DO_TILE(T)                                                              \
        {                                                                       \
            f32x4 acc = __builtin_amdgcn_mfma_f32_16x16x32_f16(cf1_##T, sf1, zero, 0, 0, 0); \
            acc       = __builtin_amdgcn_mfma_f32_16x16x32_f16(cf2_##T, sf2, acc,  0, 0, 0); \
            p0 += __builtin_amdgcn_exp2f(acc[0]);                               \
            p1 += __builtin_amdgcn_exp2f(acc[1]);                               \
            p2 += __builtin_amdgcn_exp2f(acc[2]);                               \
            p3 += __builtin_amdgcn_exp2f(acc[3]);                               \
        }

#define DO_CHUNK(CC)                                                            \
    {                                                                           \
        /* pack current chunk (consumes r0..r4) */                              \
        uint q0 = pk(r0.x, r0.y), q1 = pk(r0.z, r0.w);                          \
        uint q2 = pk(r1.x, r1.y), q3 = pk(r1.z, r1.w);                          \
        uint q4 = pk(r2.x, r2.y), q5 = pk(r2.z, r2.w);                          \
        uint q6 = pk(r3.x, r3.y), q7 = pk(r3.z, r3.w);                          \
        uint q8 = pk(r4.x, r4.y), q9 = pk(r4.z, r4.w);                          \
        /* depth-1 prefetch: dep is q9 zeroed INSIDE asm (opaque -- cannot    */ \
        /* fold or hoist). Loads for chunk CC+1 are pinned after this pack,   */ \
        /* so the scheduler can't run >1 chunk ahead (R8 spill) nor leave     */ \
        /* the load adjacent to its use (R7 exposed latency).                 */ \
        if ((CC) + 1 < CPW) {                                                   \
            uint dep = q9;                                                      \
            asm volatile("v_and_b32 %0, 0, %0" : "+v"(dep));                    \
            const float4* np = (const float4*)(sample                           \
                + (size_t)(base + ((CC) + 1) * 64 + c) * DIMS + dep);           \
            r0 = np[0]; r1 = np[1]; r2 = np[2]; r3 = np[3]; r4 = np[4];         \
        }                                                                       \
        uint s0 = pksq(q0), s1 = pksq(q1), s2 = pksq(q2), s3 = pksq(q3);        \
        uint s4 = pksq(q4), s5 = pksq(q5), s6 = pksq(q6), s7 = pksq(q7);        \
        uint s8 = pksq(q8), s9 = pksq(q9);                                      \
        uint f1_0 = qb ? (qa ? q2 : s8) : (qa ? s4 : s0);                       \
        uint f1_1 = qb ? (qa ? q3 : s9) : (qa ? s5 : s1);                       \
        uint f1_2 = qb ? (qa ? q4 : q0) : (qa ? s6 : s2);                       \
        uint f1_3 = qb ? (qa ? q5 : q1) : (qa ? s7 : s3);                       \
        uint f2_0 = qb ? 0u : (qa ? onezero : q6);                              \
        uint f2_1 = qb ? 0u : (qa ? 0u : q7);                                   \
        uint f2_2 = qb ? 0u : (qa ? 0u : q8);                                   \
        uint f2_3 = qb ? 0u : (qa ? 0u : q9);                                   \
        u32x4 w1 = { f1_0, f1_1, f1_2, f1_3 };                                  \
        u32x4 w2 = { f2_0, f2_1, f2_2, f2_3 };                                  \
        f16x8 sf1 = __builtin_bit_cast(f16x8, w1);                              \
        f16x8 sf2 = __builtin_bit_cast(f16x8, w2);                              \
        float p0 = 0.f, p1 = 0.f, p2 = 0.f, p3 = 0.f;  /* 4 indep chains */     \
        DO_TILE(0) DO_TILE(1) DO_TILE(2) DO_TILE(3) DO_TILE(4) DO_TILE(5)       \
        DO_TILE(6) DO_TILE(7) DO_TILE(8) DO_TILE(9) DO_TILE(10)                 \
        float dens = (p0 + p1) + (p2 + p3);                                     \
        dens += __shfl_xor(dens, 16, 64);                                       \
        dens += __shfl_xor(dens, 32, 64);                                       \
        if (l < 16)                                                             \
            out[base + (CC) * 64 + l] = LN2 * __builtin_amdgcn_logf(dens) + LOG_NORM; \
    }

    DO_CHUNK(0) DO_CHUNK(1) DO_CHUNK(2) DO_CHUNK(3)
    DO_CHUNK(4) DO_CHUNK(5) DO_CHUNK(6) DO_CHUNK(7)
#undef DO_CHUNK
#undef DO_TILE
}

extern "C" void kernel_launch(void* const* d_in, const int* in_sizes, int n_in,
                              void* d_out, int out_size, void* d_ws, size_t ws_size,
                              hipStream_t stream) {
    const float* sample = (const float*)d_in[0];
    const float* alpha  = (const float*)d_in[1];
    const float* mu     = (const float*)d_in[2];
    const float* cov    = (const float*)d_in[3];
    float* out = (float*)d_out;
    // N = 524288 = NB * 4 waves * CPW * 16 -- grid covers the range exactly.
    gm_fused<<<NB, 256, 0, stream>>>(sample, alpha, mu, cov, out);
}

// Round 11
// 97.057 us; speedup vs baseline: 2.2013x; 1.0053x over previous
//
#include <hip/hip_runtime.h>
#include <math.h>

// GaussianMixture log-density via f16 MFMA, round 11: two kernels.
//
//   e[k,n] = sum_j C[k][j] * F[j][n]   (base-2 exponent, fp32 MFMA accum)
//     coeff row  (A operand):  [ a2[0..19] , b2[0..19] , L2 , 0.. ]  (K=64 pad)
//     feature col(B operand):  [ x^2_0..19 , x_0..19 , 1 , 0.. ]
//   out[n] = ln( sum_k exp2(e[k,n]) ) + LOG_NORM
//
// R10 lesson: depth-1 prefetch neutral -> load latency was never the stall.
// Remaining structural costs: (a) 4 blocks/CU of work at 3 resident -> 67%
// tail efficiency; (b) per-block LDS+barrier preamble paid 4x/CU.
// R11: gm_precompute writes the coefficient table to d_ws ALREADY IN MFMA
// FRAGMENT ORDER (entry[(t*2+h)*64+lane] = the f16x8 lane needs for tile t,
// half h). gm_density: 64-thread (1-wave) blocks, 64 samples each, no LDS,
// no barriers; preamble = 22 coalesced 16B loads of the L2-resident table.
// 8192 blocks -> 32 waves/SIMD of work at 3 resident -> ~97% tail efficiency.

#define DIMS     20
#define MULT     8
#define K_COMP   168
#define KC_PAD   176            // 11 tiles of 16 components
#define NTILE    11
#define BASE_COV 0.1f
#define LOG2E    1.4426950408889634f
#define LN2      0.6931471805599453f
#define LOG_NORM -18.378770664093453f
#define CPW      4              // 16-sample chunks per wave
#define NBLK     8192           // 8192 * 64 samples = 524288 exactly

typedef _Float16 f16x8 __attribute__((ext_vector_type(8)));
typedef _Float16 f16x2 __attribute__((ext_vector_type(2)));
typedef float    f32x4 __attribute__((ext_vector_type(4)));
typedef unsigned int uint;
typedef uint u32x4 __attribute__((ext_vector_type(4)));

__device__ __forceinline__ uint pk(float lo, float hi) {
    return __builtin_bit_cast(uint, __builtin_amdgcn_cvt_pkrtz(lo, hi));
}
__device__ __forceinline__ uint pksq(uint a) {     // v_pk_mul_f16: (lo^2, hi^2)
    f16x2 v = __builtin_bit_cast(f16x2, a);
    return __builtin_bit_cast(uint, (f16x2)(v * v));
}

// ---------------- precompute: coefficient table, fragment-ordered ----------
// tbl entry e = (t*2 + h)*64 + lane  (16 B each):
//   f16x8 = C[t*16 + (lane&15)][h*32 + (lane>>4)*8 .. +7]
// where C[comp][feat]: feat 0..19 = -0.5*inv*log2e, 20..39 = mu*inv*log2e,
// 40 = L2 bias, 41..63 = 0; pad comps (>=168): all 0 except L2 = -65504.
__global__ void gm_precompute(const float* __restrict__ alpha,
                              const float* __restrict__ mu,
                              const float* __restrict__ cov,
                              uint4* __restrict__ tbl) {
    __shared__ _Float16 C[KC_PAD][64];
    __shared__ float sh_logZ;
    const int tid = threadIdx.x;

    uint* cz = (uint*)&C[0][0];
    for (int i = tid; i < KC_PAD * 64 / 2; i += 256) cz[i] = 0u;
    __syncthreads();

    if (tid < 64) {
        float a0 = (tid       < K_COMP) ? alpha[tid]       : -1e30f;
        float a1 = (tid + 64  < K_COMP) ? alpha[tid + 64]  : -1e30f;
        float a2 = (tid + 128 < K_COMP) ? alpha[tid + 128] : -1e30f;
        float m = fmaxf(fmaxf(a0, a1), a2);
        for (int msk = 32; msk; msk >>= 1) m = fmaxf(m, __shfl_xor(m, msk, 64));
        float s = __expf(a0 - m) + __expf(a1 - m) + __expf(a2 - m);
        for (int msk = 32; msk; msk >>= 1) s += __shfl_xor(s, msk, 64);
        if (tid == 0) sh_logZ = m + __logf(s);
    }
    __syncthreads();

    if (tid < K_COMP) {
        const int   n  = tid;
        const int   i  = n / MULT;
        const float fi = (float)i;
        const float var = 1.0f;                       // EPS^2, EPS = 1.0
        float logdet = fi * __logf(var) + ((float)DIMS - fi) * __logf(BASE_COV);
        float Csum = 0.0f;
        for (int d = 0; d < DIMS; ++d) {
            float scale = (d < i) ? var : 1.0f;
            float inv   = 1.0f / (cov[n * DIMS + d] * scale);
            float mm    = mu[n * DIMS + d];
            Csum += mm * mm * inv;
            C[n][d]        = (_Float16)(-0.5f * inv * LOG2E);
            C[n][DIMS + d] = (_Float16)(mm * inv * LOG2E);
        }
        float L2 = ((alpha[n] - sh_logZ) - 0.5f * logdet - 0.5f * Csum) * LOG2E;
        C[n][2 * DIMS] = (_Float16)L2;
    } else if (tid < KC_PAD) {
        C[tid][2 * DIMS] = (_Float16)(-65504.0f);     // pad comps -> exp2 -> 0
    }
    __syncthreads();

    // fragment reorder: 11 tiles * 2 halves * 64 lanes = 1408 entries
    for (int e = tid; e < NTILE * 2 * 64; e += 256) {
        int t    = e >> 7;
        int h    = (e >> 6) & 1;
        int lane = e & 63;
        int q = lane >> 4, c = lane & 15;
        tbl[e] = *(const uint4*)&C[t * 16 + c][h * 32 + q * 8];
    }
}

// ---------------- density: 1 wave per block, 64 samples, no LDS ------------
__global__ __launch_bounds__(64, 3) void gm_density(const float* __restrict__ sample,
                                                    const f16x8* __restrict__ tbl,
                                                    float* __restrict__ out) {
    const int l = threadIdx.x;          // 0..63
    const int q = l >> 4, c = l & 15;
    const bool qa = (q & 1) != 0, qb = (q & 2) != 0;
    const uint onezero = 0x00003C00u;   // pk(1.0h, 0.0h)
    const f32x4 zero = { 0.f, 0.f, 0.f, 0.f };

    // coefficient fragments: 22 coalesced 16B loads (L2-resident table)
#define LOAD_CF(T)                                                              \
    const f16x8 cf1_##T = tbl[(T) * 128 + l];                                   \
    const f16x8 cf2_##T = tbl[(T) * 128 + 64 + l];
    LOAD_CF(0) LOAD_CF(1) LOAD_CF(2) LOAD_CF(3) LOAD_CF(4) LOAD_CF(5)
    LOAD_CF(6) LOAD_CF(7) LOAD_CF(8) LOAD_CF(9) LOAD_CF(10)
#undef LOAD_CF

    const int base = blockIdx.x * (16 * CPW);

    // prefetch chunk 0
    const float4* rp0 = (const float4*)(sample + (size_t)(base + c) * DIMS);
    float4 r0 = rp0[0], r1 = rp0[1], r2 = rp0[2], r3 = rp0[3], r4 = rp0[4];

#define DO_TILE(T)                                                              \
        {                                                                       \
            f32x4 acc = __builtin_amdgcn_mfma_f32_16x16x32_f16(cf1_##T, sf1, zero, 0, 0, 0); \
            acc       = __builtin_amdgcn_mfma_f32_16x16x32_f16(cf2_##T, sf2, acc,  0, 0, 0); \
            p0 += __builtin_amdgcn_exp2f(acc[0]);                               \
            p1 += __builtin_amdgcn_exp2f(acc[1]);                               \
            p2 += __builtin_amdgcn_exp2f(acc[2]);                               \
            p3 += __builtin_amdgcn_exp2f(acc[3]);                               \
        }

#define DO_CHUNK(CC)                                                            \
    {                                                                           \
        uint q0 = pk(r0.x, r0.y), q1 = pk(r0.z, r0.w);                          \
        uint q2 = pk(r1.x, r1.y), q3 = pk(r1.z, r1.w);                          \
        uint q4 = pk(r2.x, r2.y), q5 = pk(r2.z, r2.w);                          \
        uint q6 = pk(r3.x, r3.y), q7 = pk(r3.z, r3.w);                          \
        uint q8 = pk(r4.x, r4.y), q9 = pk(r4.z, r4.w);                          \
        /* depth-1 prefetch, pinned by opaque asm (guards against R8-style   */ \
        /* multi-chunk hoist + spill; proven non-harmful in R10)             */ \
        if ((CC) + 1 < CPW) {                                                   \
            uint dep = q9;                                                      \
            asm volatile("v_and_b32 %0, 0, %0" : "+v"(dep));                    \
            const float4* np = (const float4*)(sample                           \
                + (size_t)(base + ((CC) + 1) * 16 + c) * DIMS + dep);           \
            r0 = np[0]; r1 = np[1]; r2 = np[2]; r3 = np[3]; r4 = np[4];         \
        }                                                                       \
        uint s0 = pksq(q0), s1 = pksq(q1), s2 = pksq(q2), s3 = pksq(q3);        \
        uint s4 = pksq(q4), s5 = pksq(q5), s6 = pksq(q6), s7 = pksq(q7);        \
        uint s8 = pksq(q8), s9 = pksq(q9);                                      \
        uint f1_0 = qb ? (qa ? q2 : s8) : (qa ? s4 : s0);                       \
        uint f1_1 = qb ? (qa ? q3 : s9) : (qa ? s5 : s1);                       \
        uint f1_2 = qb ? (qa ? q4 : q0) : (qa ? s6 : s2);                       \
        uint f1_3 = qb ? (qa ? q5 : q1) : (qa ? s7 : s3);                       \
        uint f2_0 = qb ? 0u : (qa ? onezero : q6);                              \
        uint f2_1 = qb ? 0u : (qa ? 0u : q7);                                   \
        uint f2_2 = qb ? 0u : (qa ? 0u : q8);                                   \
        uint f2_3 = qb ? 0u : (qa ? 0u : q9);                                   \
        u32x4 w1 = { f1_0, f1_1, f1_2, f1_3 };                                  \
        u32x4 w2 = { f2_0, f2_1, f2_2, f2_3 };                                  \
        f16x8 sf1 = __builtin_bit_cast(f16x8, w1);                              \
        f16x8 sf2 = __builtin_bit_cast(f16x8, w2);                              \
        float p0 = 0.f, p1 = 0.f, p2 = 0.f, p3 = 0.f;  /* 4 indep chains */     \
        DO_TILE(0) DO_TILE(1) DO_TILE(2) DO_TILE(3) DO_TILE(4) DO_TILE(5)       \
        DO_TILE(6) DO_TILE(7) DO_TILE(8) DO_TILE(9) DO_TILE(10)                 \
        float dens = (p0 + p1) + (p2 + p3);                                     \
        dens += __shfl_xor(dens, 16, 64);                                       \
        dens += __shfl_xor(dens, 32, 64);                                       \
        if (l < 16)                                                             \
            out[base + (CC) * 16 + l] = LN2 * __builtin_amdgcn_logf(dens) + LOG_NORM; \
    }

    DO_CHUNK(0) DO_CHUNK(1) DO_CHUNK(2) DO_CHUNK(3)
#undef DO_CHUNK
#undef DO_TILE
}

extern "C" void kernel_launch(void* const* d_in, const int* in_sizes, int n_in,
                              void* d_out, int out_size, void* d_ws, size_t ws_size,
                              hipStream_t stream) {
    const float* sample = (const float*)d_in[0];
    const float* alpha  = (const float*)d_in[1];
    const float* mu     = (const float*)d_in[2];
    const float* cov    = (const float*)d_in[3];
    float* out = (float*)d_out;
    uint4* tbl = (uint4*)d_ws;      // 11*2*64*16 B = 22528 B, fragment-ordered

    gm_precompute<<<1, 256, 0, stream>>>(alpha, mu, cov, tbl);
    gm_density<<<NBLK, 64, 0, stream>>>(sample, (const f16x8*)tbl, out);
}